// Round 5
// baseline (252.644 us; speedup 1.0000x reference)
//
#include <hip/hip_runtime.h>
#include <math.h>

#define D 1024
#define TOPK 32
#define VPT 16          // values per lane = D / 64
#define EPS 0.0625f     // bisection stop width; surp err <= ~0.01 -> out err <= ~0.002

typedef float vfloat4 __attribute__((ext_vector_type(4)));

__device__ __forceinline__ float waveSumF(float v) {
#pragma unroll
  for (int off = 32; off >= 1; off >>= 1) v += __shfl_xor(v, off, 64);
  return v;
}

// tanh-approx GELU via one v_exp + one v_rcp. |err vs erf-GELU| ~3e-4.
__device__ __forceinline__ float fast_gelu(float x) {
  const float x2 = x * x;
  const float p = __builtin_fmaf(0.044715f, x2, 1.0f);
  const float e = __expf(-1.5957691216f * x * p);
  return x * __builtin_amdgcn_rcpf(1.0f + e);
}
// tanh(y) for y>=0: 1 - 2/(exp(2y)+1); exact at +inf.
__device__ __forceinline__ float fast_tanh_pos(float y) {
  const float e = __expf(2.0f * y);
  return 1.0f - 2.0f * __builtin_amdgcn_rcpf(e + 1.0f);
}

// Wave-wide count of za[i] >= t. v_cmp -> sgpr pair -> s_bcnt: the reduce is
// free (SALU) and the result is wave-uniform.
__device__ __forceinline__ int countGE(const float* za, float t) {
  int c = 0;
#pragma unroll
  for (int i = 0; i < VPT; ++i) c += (int)__popcll(__ballot(za[i] >= t));
  return c;
}

// Prep: inv_std -> ws[0..D); exp(la),exp(ls) -> ws[D],ws[D+1].
__global__ __launch_bounds__(256) void prep_stats(const float* __restrict__ ema_mean,
                                                  const float* __restrict__ ema_sq,
                                                  const float* __restrict__ p_la,
                                                  const float* __restrict__ p_ls,
                                                  float* __restrict__ ws) {
  int i = blockIdx.x * 256 + threadIdx.x;
  if (i < D) {
    float m = ema_mean[i];
    float v = ema_sq[i] - m * m;
    ws[i] = rsqrtf(fmaxf(v, 1e-6f));
  }
  if (i == 0) {
    ws[D] = expf(p_la[0]);
    ws[D + 1] = expf(p_ls[0]);
  }
}

// Kernel A: one wave per row, compute the gate scalar only.
__global__ __launch_bounds__(256) void row_gate(const float* __restrict__ x,
                                                const float* __restrict__ ema_mean,
                                                const float* __restrict__ ws,
                                                float* __restrict__ gates,
                                                int n_rows) {
  const int wave = threadIdx.x >> 6;
  const int lane = threadIdx.x & 63;
  const int row = blockIdx.x * 4 + wave;
  if (row >= n_rows) return;
  const float* __restrict__ xr = x + (size_t)row * D;

  float za[VPT];
#pragma unroll
  for (int j = 0; j < 4; ++j) {
    const int ch = j * 256 + lane * 4;
    const float4 xx = *reinterpret_cast<const float4*>(xr + ch);
    const float4 mm = *reinterpret_cast<const float4*>(ema_mean + ch);
    const float4 ss = *reinterpret_cast<const float4*>(ws + ch);
    za[4 * j + 0] = fabsf(xx.x - mm.x) * ss.x;
    za[4 * j + 1] = fabsf(xx.y - mm.y) * ss.y;
    za[4 * j + 2] = fabsf(xx.z - mm.z) * ss.z;
    za[4 * j + 3] = fabsf(xx.w - mm.w) * ss.w;
  }

  // Bracketed bisection for the 32nd-largest value.
  // Invariants: count(za >= lo) >= TOPK (lo=0 trivially, za >= 0),
  //             count(za >= hi) <  TOPK (validated; geometric widen fallback).
  // Calibrated probes [1.2, 3.6] are ~15sigma safe for N(0,1)-like rows but
  // NOT assumed — the invariant checks make any data correct.
  float lo = 0.0f, hi = 3.6f;
  int cl = D;  // count(za >= 0) == D
  {
    const int cp = countGE(za, 1.2f);
    if (cp >= TOPK) { lo = 1.2f; cl = cp; }
  }
  {
    int chi = countGE(za, hi);
    while (chi >= TOPK) {  // hi not an upper bound: widen (finite za terminates)
      lo = hi; cl = chi;
      hi *= 2.0f;
      chi = countGE(za, hi);
    }
  }
  while (cl != TOPK && (hi - lo) > EPS) {
    const float mid = 0.5f * (lo + hi);
    const int cm = countGE(za, mid);
    if (cm >= TOPK) { lo = mid; cl = cm; }
    else hi = mid;
  }
  const float t = lo;

  // top32_sum = sum(za > t) + (TOPK - count(za > t)) * t.
  // Exact when cl == TOPK; else biased by <= (extras ~5) * EPS.
  float s = 0.0f;
  int cg = 0;
#pragma unroll
  for (int i = 0; i < VPT; ++i) {
    const bool g = za[i] > t;
    s += g ? za[i] : 0.0f;
    cg += (int)__popcll(__ballot(g));
  }
  s = waveSumF(s);
  const float surp = (s + (float)(TOPK - cg) * t) * (1.0f / (float)TOPK);
  const float gate = 1.0f + ws[D] * fast_tanh_pos(ws[D + 1] * surp);
  if (lane == 0) gates[row] = gate;
}

// Kernel B: pure stream, out = fast_gelu(x) * gate[row]. One block = one row
// per iteration; gate is a block-uniform scalar load.
__global__ __launch_bounds__(256) void apply_gate(const float* __restrict__ x,
                                                  const float* __restrict__ gates,
                                                  float* __restrict__ out,
                                                  int n_rows) {
  for (int row = blockIdx.x; row < n_rows; row += gridDim.x) {
    const float gate = gates[row];
    const size_t base = (size_t)row * D + threadIdx.x * 4;
    const float4 v = *reinterpret_cast<const float4*>(x + base);
    vfloat4 o;
    o.x = fast_gelu(v.x) * gate;
    o.y = fast_gelu(v.y) * gate;
    o.z = fast_gelu(v.z) * gate;
    o.w = fast_gelu(v.w) * gate;
    __builtin_nontemporal_store(o, reinterpret_cast<vfloat4*>(out + base));
  }
}

extern "C" void kernel_launch(void* const* d_in, const int* in_sizes, int n_in,
                              void* d_out, int out_size, void* d_ws, size_t ws_size,
                              hipStream_t stream) {
  const float* x    = (const float*)d_in[0];
  const float* la   = (const float*)d_in[1];
  const float* ls   = (const float*)d_in[2];
  const float* mean = (const float*)d_in[3];
  const float* sq   = (const float*)d_in[4];
  float* out = (float*)d_out;
  float* ws = (float*)d_ws;           // [0..D): inv_std, [D],[D+1]: e^la,e^ls
  float* gates = ws + 2048;           // [2048 .. 2048+n_rows): per-row gate

  const int n = in_sizes[0];
  const int n_rows = n / D;

  prep_stats<<<(D + 255) / 256, 256, 0, stream>>>(mean, sq, la, ls, ws);

  row_gate<<<(n_rows + 3) / 4, 256, 0, stream>>>(x, mean, ws, gates, n_rows);

  const int gridB = 8192;             // 4 rows per block at n_rows = 32768
  apply_gate<<<gridB, 256, 0, stream>>>(x, gates, out, n_rows);
}